// Round 1
// baseline (941.552 us; speedup 1.0000x reference)
//
#include <hip/hip_runtime.h>

// Shapes
#define B_   128
#define S_   400
#define H_   512
#define V_   50257
#define VX_  50307

// Output offsets (floats, concatenated in return order)
#define OFF_FINAL 0
#define OFF_PGEN  6439296
#define OFF_ATTN  6439424
#define OFF_COV   6490624
#define OFF_H1    6541824
#define OFF_C1    6607360
#define OFF_DEC   6672896

static __device__ __forceinline__ float sigmoid_f(float x) {
    return 1.0f / (1.0f + __expf(-x));
}
static __device__ __forceinline__ float tanh_f(float x) {
    // tanh(x) = 1 - 2/(exp(2x)+1); stable at both extremes
    return 1.0f - 2.0f / (__expf(2.0f * x) + 1.0f);
}

// ---------------------------------------------------------------------------
// Generic C[128 x N] = A[128 x 512] @ W[N x >=512]^T (+ bias) (+ C if beta)
// A row stride = lda, W row stride = ldw, W column offset = kwoff. K fixed 512.
// Tile: 128m x 64n, BK=16, 256 threads, 8m x 4n accumulators per thread.
// ---------------------------------------------------------------------------
__global__ __launch_bounds__(256) void gemm_xwt(
    const float* __restrict__ A, int lda,
    const float* __restrict__ W, int ldw, int kwoff,
    const float* __restrict__ bias,
    float* __restrict__ C, int N, int beta)
{
    __shared__ float As[16][128];
    __shared__ float Ws[16][64];
    const int tid = threadIdx.x;
    const int bn0 = blockIdx.x * 64;
    const int tx = tid & 15;
    const int ty = tid >> 4;

    float acc[8][4];
#pragma unroll
    for (int i = 0; i < 8; ++i)
#pragma unroll
        for (int j = 0; j < 4; ++j) acc[i][j] = 0.0f;

    const int am = tid >> 1;        // 0..127
    const int ak = (tid & 1) << 3;  // 0 or 8
    const int wn = tid >> 2;        // 0..63
    const int wk = (tid & 3) << 2;  // 0,4,8,12
    const int wng = bn0 + wn;
    const bool wv = (wng < N);
    const float* Ap = A + (long)am * lda + ak;
    const float* Wp = W + (long)(wv ? wng : 0) * ldw + kwoff + wk;

    for (int k0 = 0; k0 < 512; k0 += 16) {
        float4 a0 = *(const float4*)(Ap + k0);
        float4 a1 = *(const float4*)(Ap + k0 + 4);
        float4 w0 = make_float4(0.f, 0.f, 0.f, 0.f);
        if (wv) w0 = *(const float4*)(Wp + k0);
        __syncthreads();  // previous iteration's LDS reads done
        As[ak + 0][am] = a0.x; As[ak + 1][am] = a0.y;
        As[ak + 2][am] = a0.z; As[ak + 3][am] = a0.w;
        As[ak + 4][am] = a1.x; As[ak + 5][am] = a1.y;
        As[ak + 6][am] = a1.z; As[ak + 7][am] = a1.w;
        Ws[wk + 0][wn] = w0.x; Ws[wk + 1][wn] = w0.y;
        Ws[wk + 2][wn] = w0.z; Ws[wk + 3][wn] = w0.w;
        __syncthreads();
#pragma unroll
        for (int kk = 0; kk < 16; ++kk) {
            const float4 av0 = *(const float4*)&As[kk][ty << 3];
            const float4 av1 = *(const float4*)&As[kk][(ty << 3) + 4];
            const float4 wv4 = *(const float4*)&Ws[kk][tx << 2];
            const float a[8] = {av0.x, av0.y, av0.z, av0.w, av1.x, av1.y, av1.z, av1.w};
            const float w[4] = {wv4.x, wv4.y, wv4.z, wv4.w};
#pragma unroll
            for (int i = 0; i < 8; ++i)
#pragma unroll
                for (int j = 0; j < 4; ++j) acc[i][j] = fmaf(a[i], w[j], acc[i][j]);
        }
    }

#pragma unroll
    for (int i = 0; i < 8; ++i) {
        const int m = (ty << 3) + i;
        float* Crow = C + (long)m * N;
#pragma unroll
        for (int j = 0; j < 4; ++j) {
            const int n = bn0 + (tx << 2) + j;
            if (n < N) {
                float v = acc[i][j];
                if (bias) v += bias[n];
                if (beta) v += Crow[n];
                Crow[n] = v;
            }
        }
    }
}

// LSTM cell elementwise: gates (B x 2048) -> h1, c1 (B x 512)
__global__ __launch_bounds__(256) void lstm_cell(
    const float* __restrict__ gates, const float* __restrict__ c0,
    float* __restrict__ h1, float* __restrict__ c1)
{
    const int idx = blockIdx.x * 256 + threadIdx.x;  // 65536
    const int b = idx >> 9, h = idx & 511;
    const float* g = gates + ((long)b << 11);
    const float gi = sigmoid_f(g[h]);
    const float gf = sigmoid_f(g[h + 512]);
    const float gg = tanh_f(g[h + 1024]);
    const float go = sigmoid_f(g[h + 1536]);
    const float c = gf * c0[idx] + gi * gg;
    c1[idx] = c;
    h1[idx] = go * tanh_f(c);
}

// e[b,s] = sum_h tanh(sf[b,s,h] + dec_fea[b,h] + wc*cov[b,s]) * v_att[h]
// one wave per (b,s); 4 waves per block
__global__ __launch_bounds__(256) void attn_scores(
    const float* __restrict__ sfeat, const float* __restrict__ decfea,
    const float* __restrict__ cov, const float* __restrict__ wc,
    const float* __restrict__ vatt, float* __restrict__ e)
{
    const int lane = threadIdx.x & 63;
    const int pair = blockIdx.x * 4 + (threadIdx.x >> 6);  // b*400+s
    const int b = pair / 400;
    const float cc = wc[0] * cov[pair];
    const float* sp = sfeat + ((long)pair << 9) + (lane << 3);
    const float* dp = decfea + (b << 9) + (lane << 3);
    const float* vp = vatt + (lane << 3);
    const float4 s0 = *(const float4*)sp, s1 = *(const float4*)(sp + 4);
    const float4 d0 = *(const float4*)dp, d1 = *(const float4*)(dp + 4);
    const float4 v0 = *(const float4*)vp, v1 = *(const float4*)(vp + 4);
    float acc = tanh_f(s0.x + d0.x + cc) * v0.x
              + tanh_f(s0.y + d0.y + cc) * v0.y
              + tanh_f(s0.z + d0.z + cc) * v0.z
              + tanh_f(s0.w + d0.w + cc) * v0.w
              + tanh_f(s1.x + d1.x + cc) * v1.x
              + tanh_f(s1.y + d1.y + cc) * v1.y
              + tanh_f(s1.z + d1.z + cc) * v1.z
              + tanh_f(s1.w + d1.w + cc) * v1.w;
#pragma unroll
    for (int off = 32; off > 0; off >>= 1) acc += __shfl_down(acc, off);
    if (lane == 0) e[pair] = acc;
}

// Masked softmax over S per batch row + coverage update; also zeroes ctx accum.
__global__ __launch_bounds__(256) void attn_softmax(
    const float* __restrict__ e, const float* __restrict__ mask,
    const float* __restrict__ cov,
    float* __restrict__ attn, float* __restrict__ covnew, float* __restrict__ ctx)
{
    __shared__ float sm[4], sps[4], spms[4];
    const int b = blockIdx.x, tid = threadIdx.x;
    ctx[(b << 9) + tid] = 0.f;
    ctx[(b << 9) + 256 + tid] = 0.f;

    float vals[2], msk[2];
    float m = -3.0e38f;
#pragma unroll
    for (int it = 0; it < 2; ++it) {
        const int s = tid + (it << 8);
        float mk = 0.f, v = -3.0e38f;
        if (s < 400) {
            mk = mask[b * 400 + s];
            v = (mk > 0.f) ? e[b * 400 + s] : -1.0e9f;
        }
        vals[it] = v; msk[it] = mk;
        m = fmaxf(m, v);
    }
#pragma unroll
    for (int off = 32; off > 0; off >>= 1) m = fmaxf(m, __shfl_down(m, off));
    if ((tid & 63) == 0) sm[tid >> 6] = m;
    __syncthreads();
    const float M = fmaxf(fmaxf(sm[0], sm[1]), fmaxf(sm[2], sm[3]));

    float p[2], sp = 0.f, spm = 0.f;
#pragma unroll
    for (int it = 0; it < 2; ++it) {
        const int s = tid + (it << 8);
        float pv = 0.f;
        if (s < 400) pv = __expf(vals[it] - M);
        p[it] = pv; sp += pv; spm += pv * msk[it];
    }
#pragma unroll
    for (int off = 32; off > 0; off >>= 1) {
        sp += __shfl_down(sp, off);
        spm += __shfl_down(spm, off);
    }
    if ((tid & 63) == 0) { sps[tid >> 6] = sp; spms[tid >> 6] = spm; }
    __syncthreads();
    const float SP = sps[0] + sps[1] + sps[2] + sps[3];
    const float SPM = spms[0] + spms[1] + spms[2] + spms[3];
    // attn = (p*mask/SP) / (SPM/SP + 1e-12) = p*mask / (SPM + 1e-12*SP)
    const float inv = 1.0f / (SPM + 1e-12f * SP);
#pragma unroll
    for (int it = 0; it < 2; ++it) {
        const int s = tid + (it << 8);
        if (s < 400) {
            const float a = p[it] * msk[it] * inv;
            attn[b * 400 + s] = a;
            covnew[b * 400 + s] = cov[b * 400 + s] + a;
        }
    }
}

// ctx[b,h] += sum over an s-chunk of attn[b,s]*states[b,s,h]; 4 chunks per b
__global__ __launch_bounds__(256) void ctx_kernel(
    const float* __restrict__ attn, const float* __restrict__ states,
    float* __restrict__ ctx)
{
    const int bx = blockIdx.x;  // 512
    const int b = bx >> 2, chunk = bx & 3;
    const int tid = threadIdx.x;
    const int c = tid & 127;   // float4 column
    const int sh = tid >> 7;   // 0..1
    const int s0 = chunk * 100 + sh;
    const float* base = states + (long)b * 400 * 512;
    float4 acc = make_float4(0.f, 0.f, 0.f, 0.f);
    for (int i = 0; i < 50; ++i) {
        const int s = s0 + (i << 1);
        const float a = attn[b * 400 + s];
        const float4 st = *(const float4*)(base + (long)s * 512 + (c << 2));
        acc.x = fmaf(a, st.x, acc.x);
        acc.y = fmaf(a, st.y, acc.y);
        acc.z = fmaf(a, st.z, acc.z);
        acc.w = fmaf(a, st.w, acc.w);
    }
    float* cp = ctx + (b << 9) + (c << 2);
    atomicAdd(cp + 0, acc.x);
    atomicAdd(cp + 1, acc.y);
    atomicAdd(cp + 2, acc.z);
    atomicAdd(cp + 3, acc.w);
}

// p_gen[b] = sigmoid(dec_out[b,:]·W_pg + b_pg); one wave per b
__global__ __launch_bounds__(64) void pgen_kernel(
    const float* __restrict__ dec_out, const float* __restrict__ wpg,
    const float* __restrict__ bpg, float* __restrict__ pgen)
{
    const int b = blockIdx.x, lane = threadIdx.x;
    const float* dp = dec_out + (b << 9) + (lane << 3);
    const float* wp = wpg + (lane << 3);
    const float4 d0 = *(const float4*)dp, d1 = *(const float4*)(dp + 4);
    const float4 w0 = *(const float4*)wp, w1 = *(const float4*)(wp + 4);
    float acc = d0.x * w0.x + d0.y * w0.y + d0.z * w0.z + d0.w * w0.w
              + d1.x * w1.x + d1.y * w1.y + d1.z * w1.z + d1.w * w1.w;
#pragma unroll
    for (int off = 32; off > 0; off >>= 1) acc += __shfl_down(acc, off);
    if (lane == 0) pgen[b] = sigmoid_f(acc + bpg[0]);
}

// per-row max & sum(exp) over V
__global__ __launch_bounds__(256) void row_stats(
    const float* __restrict__ logits, float* __restrict__ rmax, float* __restrict__ rsum)
{
    __shared__ float sm[4];
    const int b = blockIdx.x, tid = threadIdx.x;
    const float* row = logits + (long)b * V_;
    float m = -3.0e38f;
    for (int v = tid; v < V_; v += 256) m = fmaxf(m, row[v]);
#pragma unroll
    for (int off = 32; off > 0; off >>= 1) m = fmaxf(m, __shfl_down(m, off));
    if ((tid & 63) == 0) sm[tid >> 6] = m;
    __syncthreads();
    const float M = fmaxf(fmaxf(sm[0], sm[1]), fmaxf(sm[2], sm[3]));
    float s = 0.f;
    for (int v = tid; v < V_; v += 256) s += __expf(row[v] - M);
#pragma unroll
    for (int off = 32; off > 0; off >>= 1) s += __shfl_down(s, off);
    __syncthreads();
    if ((tid & 63) == 0) sm[tid >> 6] = s;
    __syncthreads();
    if (tid == 0) { rmax[b] = M; rsum[b] = sm[0] + sm[1] + sm[2] + sm[3]; }
}

// final[b, v<V] = p_gen*softmax(logits); final[b, V..VEXT) = 0
__global__ __launch_bounds__(256) void final_write(
    const float* __restrict__ logits, const float* __restrict__ rmax,
    const float* __restrict__ rsum, const float* __restrict__ pgen,
    float* __restrict__ final)
{
    const int b = blockIdx.y;
    const int v0 = (blockIdx.x * 256 + threadIdx.x) << 2;
    if (v0 >= VX_) return;
    const float M = rmax[b];
    const float sc = pgen[b] / rsum[b];
    const float* row = logits + (long)b * V_;
    float* out = final + (long)b * VX_ + v0;
#pragma unroll
    for (int j = 0; j < 4; ++j) {
        const int v = v0 + j;
        if (v < VX_) out[j] = (v < V_) ? __expf(row[v] - M) * sc : 0.f;
    }
}

// scatter-add copy distribution
__global__ __launch_bounds__(256) void scatter_kernel(
    const int* __restrict__ ids, const float* __restrict__ attn,
    const float* __restrict__ pgen, float* __restrict__ final)
{
    const int s = blockIdx.x * 256 + threadIdx.x;
    const int b = blockIdx.y;
    if (s < 400) {
        const float v = (1.0f - pgen[b]) * attn[b * 400 + s];
        atomicAdd(final + (long)b * VX_ + ids[b * 400 + s], v);
    }
}

extern "C" void kernel_launch(void* const* d_in, const int* in_sizes, int n_in,
                              void* d_out, int out_size, void* d_ws, size_t ws_size,
                              hipStream_t stream)
{
    const float* input_emb  = (const float*)d_in[0];
    const float* input_feed = (const float*)d_in[1];
    const float* hidden     = (const float*)d_in[2];
    const float* context    = (const float*)d_in[3];
    const float* states     = (const float*)d_in[4];
    const float* sfeat      = (const float*)d_in[5];
    const float* mask       = (const float*)d_in[6];
    const float* cov        = (const float*)d_in[7];
    const int*   src_ids    = (const int*)d_in[8];
    const float* W_ic  = (const float*)d_in[9];
    const float* b_ic  = (const float*)d_in[10];
    const float* W_ih  = (const float*)d_in[11];
    const float* W_hh  = (const float*)d_in[12];
    const float* b_ih  = (const float*)d_in[13];
    const float* b_hh  = (const float*)d_in[14];
    const float* W_dec = (const float*)d_in[15];
    const float* b_att = (const float*)d_in[16];
    const float* v_att = (const float*)d_in[17];
    const float* w_c   = (const float*)d_in[18];
    const float* W_out = (const float*)d_in[19];
    const float* b_out = (const float*)d_in[20];
    const float* W_pg  = (const float*)d_in[21];
    const float* b_pg  = (const float*)d_in[22];
    const float* W_v   = (const float*)d_in[23];
    const float* b_v   = (const float*)d_in[24];

    float* out = (float*)d_out;
    float* o_final = out + OFF_FINAL;
    float* o_pgen  = out + OFF_PGEN;
    float* o_attn  = out + OFF_ATTN;
    float* o_cov   = out + OFF_COV;
    float* o_h1    = out + OFF_H1;
    float* o_c1    = out + OFF_C1;
    float* o_dec   = out + OFF_DEC;

    float* ws = (float*)d_ws;
    float* w_x      = ws;            // 128*512
    float* w_gates  = ws + 65536;    // 128*2048
    float* w_decfea = ws + 327680;   // 128*512
    float* w_e      = ws + 393216;   // 128*400
    float* w_ctx    = ws + 444416;   // 128*512
    float* w_logits = ws + 509952;   // 128*50257
    float* w_rmax   = ws + 6942848;  // 128
    float* w_rsum   = ws + 6942976;  // 128

    const dim3 blk(256);
    // x = [emb, feed] @ W_ic^T + b_ic
    gemm_xwt<<<8, blk, 0, stream>>>(input_emb, 512, W_ic, 1024, 0, b_ic, w_x, 512, 0);
    gemm_xwt<<<8, blk, 0, stream>>>(input_feed, 512, W_ic, 1024, 512, nullptr, w_x, 512, 1);
    // gates = x @ W_ih^T + b_ih + h0 @ W_hh^T + b_hh ; LSTM cell
    gemm_xwt<<<32, blk, 0, stream>>>(w_x, 512, W_ih, 512, 0, b_ih, w_gates, 2048, 0);
    gemm_xwt<<<32, blk, 0, stream>>>(hidden, 512, W_hh, 512, 0, b_hh, w_gates, 2048, 1);
    lstm_cell<<<256, blk, 0, stream>>>(w_gates, context, o_h1, o_c1);
    // dec_fea = h1 @ W_dec^T + b_att
    gemm_xwt<<<8, blk, 0, stream>>>(o_h1, 512, W_dec, 512, 0, b_att, w_decfea, 512, 0);
    // attention
    attn_scores<<<12800, blk, 0, stream>>>(sfeat, w_decfea, cov, w_c, v_att, w_e);
    attn_softmax<<<128, blk, 0, stream>>>(w_e, mask, cov, o_attn, o_cov, w_ctx);
    ctx_kernel<<<512, blk, 0, stream>>>(o_attn, states, w_ctx);
    // dec_out = [h1, ctx] @ W_out^T + b_out
    gemm_xwt<<<8, blk, 0, stream>>>(o_h1, 512, W_out, 1024, 0, b_out, o_dec, 512, 0);
    gemm_xwt<<<8, blk, 0, stream>>>(w_ctx, 512, W_out, 1024, 512, nullptr, o_dec, 512, 1);
    pgen_kernel<<<128, dim3(64), 0, stream>>>(o_dec, W_pg, b_pg, o_pgen);
    // vocab logits + softmax + final distribution
    gemm_xwt<<<786, blk, 0, stream>>>(o_dec, 512, W_v, 512, 0, b_v, w_logits, 50257, 0);
    row_stats<<<128, blk, 0, stream>>>(w_logits, w_rmax, w_rsum);
    final_write<<<dim3(50, 128), blk, 0, stream>>>(w_logits, w_rmax, w_rsum, o_pgen, o_final);
    scatter_kernel<<<dim3(2, 128), blk, 0, stream>>>(src_ids, o_attn, o_pgen, o_final);
}

// Round 2
// 616.606 us; speedup vs baseline: 1.5270x; 1.5270x over previous
//
#include <hip/hip_runtime.h>

// Shapes
#define B_   128
#define S_   400
#define H_   512
#define V_   50257
#define VX_  50307

// Output offsets (floats, concatenated in return order)
#define OFF_FINAL 0
#define OFF_PGEN  6439296
#define OFF_ATTN  6439424
#define OFF_COV   6490624
#define OFF_H1    6541824
#define OFF_C1    6607360
#define OFF_DEC   6672896

typedef __attribute__((ext_vector_type(8))) short bf16x8;
typedef __attribute__((ext_vector_type(4))) float f32x4;

static __device__ __forceinline__ float sigmoid_f(float x) {
    return 1.0f / (1.0f + __expf(-x));
}
static __device__ __forceinline__ float tanh_f(float x) {
    return 1.0f - 2.0f / (__expf(2.0f * x) + 1.0f);
}
// f32 -> bf16 round-to-nearest-even, two at a time packed into a uint
static __device__ __forceinline__ unsigned int pack2(float x, float y) {
    unsigned int a = __float_as_uint(x);
    unsigned int b = __float_as_uint(y);
    a = (a + 0x7FFFu + ((a >> 16) & 1u)) >> 16;
    b = (b + 0x7FFFu + ((b >> 16) & 1u)) >> 16;
    return a | (b << 16);
}

// ---------------------------------------------------------------------------
// C[128 x N] = A1[128x512] @ W1^T + (A2 ? A2[128x512] @ W2^T : 0) + bias1 (+bias2)
// W row stride ldw, column offset kwo (for concat-weight views). A row stride 512.
// bf16 MFMA 16x16x32. Block: 256 thr (4 waves), tile M=128 x N=64, BK=32.
// LDS rows padded 32->40 bf16 (80 B = 20 banks -> 2-way max on frag reads, free).
// ---------------------------------------------------------------------------
__global__ __launch_bounds__(256) void gemm_mfma(
    const float* __restrict__ A1, const float* __restrict__ W1, int ldw1, int kwo1,
    const float* __restrict__ A2, const float* __restrict__ W2, int ldw2, int kwo2,
    const float* __restrict__ bias1, const float* __restrict__ bias2,
    float* __restrict__ C, int N)
{
    __shared__ __align__(16) unsigned short As[128 * 40];
    __shared__ __align__(16) unsigned short Ws[64 * 40];
    const int tid  = threadIdx.x;
    const int bn0  = blockIdx.x * 64;
    const int lane = tid & 63;
    const int wv   = tid >> 6;     // wave 0..3 -> m-range wv*32
    const int quad = lane >> 4;    // 0..3
    const int col  = lane & 15;

    f32x4 acc[2][4];
#pragma unroll
    for (int i = 0; i < 2; ++i)
#pragma unroll
        for (int j = 0; j < 4; ++j) acc[i][j] = (f32x4){0.f, 0.f, 0.f, 0.f};

    // staging assignment
    const int ar = tid >> 1;             // A row 0..127
    const int ac = (tid & 1) << 4;       // A col 0 or 16
    const int wr = tid >> 2;             // W tile-row 0..63
    const int wc = (tid & 3) << 3;       // W col 0,8,16,24
    const int wrg = (bn0 + wr < N) ? (bn0 + wr) : (N - 1);

    const int nph = (A2 != nullptr) ? 2 : 1;
    for (int ph = 0; ph < nph; ++ph) {
        const float* A   = ph ? A2 : A1;
        const float* W   = ph ? W2 : W1;
        const int    ldw = ph ? ldw2 : ldw1;
        const int    kwo = ph ? kwo2 : kwo1;
        const float* Ap = A + (long)ar * 512 + ac;
        const float* Wp = W + (long)wrg * ldw + kwo + wc;

        for (int k0 = 0; k0 < 512; k0 += 32) {
            const float4 a0 = *(const float4*)(Ap + k0);
            const float4 a1 = *(const float4*)(Ap + k0 + 4);
            const float4 a2 = *(const float4*)(Ap + k0 + 8);
            const float4 a3 = *(const float4*)(Ap + k0 + 12);
            const float4 w0 = *(const float4*)(Wp + k0);
            const float4 w1 = *(const float4*)(Wp + k0 + 4);
            __syncthreads();  // previous iter's LDS reads complete
            uint4* apd = (uint4*)&As[ar * 40 + ac];
            apd[0] = make_uint4(pack2(a0.x, a0.y), pack2(a0.z, a0.w),
                                pack2(a1.x, a1.y), pack2(a1.z, a1.w));
            apd[1] = make_uint4(pack2(a2.x, a2.y), pack2(a2.z, a2.w),
                                pack2(a3.x, a3.y), pack2(a3.z, a3.w));
            *(uint4*)&Ws[wr * 40 + wc] =
                make_uint4(pack2(w0.x, w0.y), pack2(w0.z, w0.w),
                           pack2(w1.x, w1.y), pack2(w1.z, w1.w));
            __syncthreads();

            // fragments: A[m=lane&15][k=quad*8+j], B[k=quad*8+j][n=lane&15] = W[n][k]
            const bf16x8 aF0 = *(const bf16x8*)&As[(wv * 32 + col) * 40 + quad * 8];
            const bf16x8 aF1 = *(const bf16x8*)&As[(wv * 32 + 16 + col) * 40 + quad * 8];
            const bf16x8 bF0 = *(const bf16x8*)&Ws[(col) * 40 + quad * 8];
            const bf16x8 bF1 = *(const bf16x8*)&Ws[(16 + col) * 40 + quad * 8];
            const bf16x8 bF2 = *(const bf16x8*)&Ws[(32 + col) * 40 + quad * 8];
            const bf16x8 bF3 = *(const bf16x8*)&Ws[(48 + col) * 40 + quad * 8];
            acc[0][0] = __builtin_amdgcn_mfma_f32_16x16x32_bf16(aF0, bF0, acc[0][0], 0, 0, 0);
            acc[0][1] = __builtin_amdgcn_mfma_f32_16x16x32_bf16(aF0, bF1, acc[0][1], 0, 0, 0);
            acc[0][2] = __builtin_amdgcn_mfma_f32_16x16x32_bf16(aF0, bF2, acc[0][2], 0, 0, 0);
            acc[0][3] = __builtin_amdgcn_mfma_f32_16x16x32_bf16(aF0, bF3, acc[0][3], 0, 0, 0);
            acc[1][0] = __builtin_amdgcn_mfma_f32_16x16x32_bf16(aF1, bF0, acc[1][0], 0, 0, 0);
            acc[1][1] = __builtin_amdgcn_mfma_f32_16x16x32_bf16(aF1, bF1, acc[1][1], 0, 0, 0);
            acc[1][2] = __builtin_amdgcn_mfma_f32_16x16x32_bf16(aF1, bF2, acc[1][2], 0, 0, 0);
            acc[1][3] = __builtin_amdgcn_mfma_f32_16x16x32_bf16(aF1, bF3, acc[1][3], 0, 0, 0);
        }
    }

    // epilogue: C/D layout col=lane&15, row=quad*4+reg
#pragma unroll
    for (int mi = 0; mi < 2; ++mi) {
#pragma unroll
        for (int ni = 0; ni < 4; ++ni) {
            const int n = bn0 + ni * 16 + col;
            if (n < N) {
                float bv = bias1[n];
                if (bias2) bv += bias2[n];
#pragma unroll
                for (int r = 0; r < 4; ++r) {
                    const int m = wv * 32 + mi * 16 + quad * 4 + r;
                    C[(long)m * N + n] = acc[mi][ni][r] + bv;
                }
            }
        }
    }
}

// LSTM cell elementwise: gates (B x 2048) -> h1, c1 (B x 512)
__global__ __launch_bounds__(256) void lstm_cell(
    const float* __restrict__ gates, const float* __restrict__ c0,
    float* __restrict__ h1, float* __restrict__ c1)
{
    const int idx = blockIdx.x * 256 + threadIdx.x;  // 65536
    const int b = idx >> 9, h = idx & 511;
    const float* g = gates + ((long)b << 11);
    const float gi = sigmoid_f(g[h]);
    const float gf = sigmoid_f(g[h + 512]);
    const float gg = tanh_f(g[h + 1024]);
    const float go = sigmoid_f(g[h + 1536]);
    const float c = gf * c0[idx] + gi * gg;
    c1[idx] = c;
    h1[idx] = go * tanh_f(c);
}

// e[b,s] = sum_h tanh(sf[b,s,h] + dec_fea[b,h] + wc*cov[b,s]) * v_att[h]
__global__ __launch_bounds__(256) void attn_scores(
    const float* __restrict__ sfeat, const float* __restrict__ decfea,
    const float* __restrict__ cov, const float* __restrict__ wc,
    const float* __restrict__ vatt, float* __restrict__ e)
{
    const int lane = threadIdx.x & 63;
    const int pair = blockIdx.x * 4 + (threadIdx.x >> 6);  // b*400+s
    const int b = pair / 400;
    const float cc = wc[0] * cov[pair];
    const float* sp = sfeat + ((long)pair << 9) + (lane << 3);
    const float* dp = decfea + (b << 9) + (lane << 3);
    const float* vp = vatt + (lane << 3);
    const float4 s0 = *(const float4*)sp, s1 = *(const float4*)(sp + 4);
    const float4 d0 = *(const float4*)dp, d1 = *(const float4*)(dp + 4);
    const float4 v0 = *(const float4*)vp, v1 = *(const float4*)(vp + 4);
    float acc = tanh_f(s0.x + d0.x + cc) * v0.x
              + tanh_f(s0.y + d0.y + cc) * v0.y
              + tanh_f(s0.z + d0.z + cc) * v0.z
              + tanh_f(s0.w + d0.w + cc) * v0.w
              + tanh_f(s1.x + d1.x + cc) * v1.x
              + tanh_f(s1.y + d1.y + cc) * v1.y
              + tanh_f(s1.z + d1.z + cc) * v1.z
              + tanh_f(s1.w + d1.w + cc) * v1.w;
#pragma unroll
    for (int off = 32; off > 0; off >>= 1) acc += __shfl_down(acc, off);
    if (lane == 0) e[pair] = acc;
}

// Masked softmax over S per batch row + coverage update; also zeroes ctx accum.
__global__ __launch_bounds__(256) void attn_softmax(
    const float* __restrict__ e, const float* __restrict__ mask,
    const float* __restrict__ cov,
    float* __restrict__ attn, float* __restrict__ covnew, float* __restrict__ ctx)
{
    __shared__ float sm[4], sps[4], spms[4];
    const int b = blockIdx.x, tid = threadIdx.x;
    ctx[(b << 9) + tid] = 0.f;
    ctx[(b << 9) + 256 + tid] = 0.f;

    float vals[2], msk[2];
    float m = -3.0e38f;
#pragma unroll
    for (int it = 0; it < 2; ++it) {
        const int s = tid + (it << 8);
        float mk = 0.f, v = -3.0e38f;
        if (s < 400) {
            mk = mask[b * 400 + s];
            v = (mk > 0.f) ? e[b * 400 + s] : -1.0e9f;
        }
        vals[it] = v; msk[it] = mk;
        m = fmaxf(m, v);
    }
#pragma unroll
    for (int off = 32; off > 0; off >>= 1) m = fmaxf(m, __shfl_down(m, off));
    if ((tid & 63) == 0) sm[tid >> 6] = m;
    __syncthreads();
    const float M = fmaxf(fmaxf(sm[0], sm[1]), fmaxf(sm[2], sm[3]));

    float p[2], sp = 0.f, spm = 0.f;
#pragma unroll
    for (int it = 0; it < 2; ++it) {
        const int s = tid + (it << 8);
        float pv = 0.f;
        if (s < 400) pv = __expf(vals[it] - M);
        p[it] = pv; sp += pv; spm += pv * msk[it];
    }
#pragma unroll
    for (int off = 32; off > 0; off >>= 1) {
        sp += __shfl_down(sp, off);
        spm += __shfl_down(spm, off);
    }
    if ((tid & 63) == 0) { sps[tid >> 6] = sp; spms[tid >> 6] = spm; }
    __syncthreads();
    const float SP = sps[0] + sps[1] + sps[2] + sps[3];
    const float SPM = spms[0] + spms[1] + spms[2] + spms[3];
    const float inv = 1.0f / (SPM + 1e-12f * SP);
#pragma unroll
    for (int it = 0; it < 2; ++it) {
        const int s = tid + (it << 8);
        if (s < 400) {
            const float a = p[it] * msk[it] * inv;
            attn[b * 400 + s] = a;
            covnew[b * 400 + s] = cov[b * 400 + s] + a;
        }
    }
}

// ctx[b,h] += sum over an s-chunk of attn[b,s]*states[b,s,h]; 4 chunks per b
__global__ __launch_bounds__(256) void ctx_kernel(
    const float* __restrict__ attn, const float* __restrict__ states,
    float* __restrict__ ctx)
{
    const int bx = blockIdx.x;  // 512
    const int b = bx >> 2, chunk = bx & 3;
    const int tid = threadIdx.x;
    const int c = tid & 127;
    const int sh = tid >> 7;
    const int s0 = chunk * 100 + sh;
    const float* base = states + (long)b * 400 * 512;
    float4 acc = make_float4(0.f, 0.f, 0.f, 0.f);
    for (int i = 0; i < 50; ++i) {
        const int s = s0 + (i << 1);
        const float a = attn[b * 400 + s];
        const float4 st = *(const float4*)(base + (long)s * 512 + (c << 2));
        acc.x = fmaf(a, st.x, acc.x);
        acc.y = fmaf(a, st.y, acc.y);
        acc.z = fmaf(a, st.z, acc.z);
        acc.w = fmaf(a, st.w, acc.w);
    }
    float* cp = ctx + (b << 9) + (c << 2);
    atomicAdd(cp + 0, acc.x);
    atomicAdd(cp + 1, acc.y);
    atomicAdd(cp + 2, acc.z);
    atomicAdd(cp + 3, acc.w);
}

// p_gen[b] = sigmoid(dec_out[b,:]·W_pg + b_pg)
__global__ __launch_bounds__(64) void pgen_kernel(
    const float* __restrict__ dec_out, const float* __restrict__ wpg,
    const float* __restrict__ bpg, float* __restrict__ pgen)
{
    const int b = blockIdx.x, lane = threadIdx.x;
    const float* dp = dec_out + (b << 9) + (lane << 3);
    const float* wp = wpg + (lane << 3);
    const float4 d0 = *(const float4*)dp, d1 = *(const float4*)(dp + 4);
    const float4 w0 = *(const float4*)wp, w1 = *(const float4*)(wp + 4);
    float acc = d0.x * w0.x + d0.y * w0.y + d0.z * w0.z + d0.w * w0.w
              + d1.x * w1.x + d1.y * w1.y + d1.z * w1.z + d1.w * w1.w;
#pragma unroll
    for (int off = 32; off > 0; off >>= 1) acc += __shfl_down(acc, off);
    if (lane == 0) pgen[b] = sigmoid_f(acc + bpg[0]);
}

// single-pass online per-row max & sum(exp) over V
__global__ __launch_bounds__(256) void row_stats(
    const float* __restrict__ logits, float* __restrict__ rmax, float* __restrict__ rsum)
{
    __shared__ float smx[4], ssx[4];
    const int b = blockIdx.x, tid = threadIdx.x;
    const float* row = logits + (long)b * V_;
    float m = -3.0e38f, s = 0.f;
    for (int v = tid; v < V_; v += 256) {
        const float x = row[v];
        const float M = fmaxf(m, x);
        s = s * __expf(m - M) + __expf(x - M);
        m = M;
    }
#pragma unroll
    for (int off = 32; off > 0; off >>= 1) {
        const float m2 = __shfl_down(m, off);
        const float s2 = __shfl_down(s, off);
        const float M = fmaxf(m, m2);
        s = s * __expf(m - M) + s2 * __expf(m2 - M);
        m = M;
    }
    if ((tid & 63) == 0) { smx[tid >> 6] = m; ssx[tid >> 6] = s; }
    __syncthreads();
    if (tid == 0) {
        float M = fmaxf(fmaxf(smx[0], smx[1]), fmaxf(smx[2], smx[3]));
        float S = ssx[0] * __expf(smx[0] - M) + ssx[1] * __expf(smx[1] - M)
                + ssx[2] * __expf(smx[2] - M) + ssx[3] * __expf(smx[3] - M);
        rmax[b] = M; rsum[b] = S;
    }
}

// final[b, v<V] = p_gen*softmax(logits); final[b, V..VEXT) = 0
__global__ __launch_bounds__(256) void final_write(
    const float* __restrict__ logits, const float* __restrict__ rmax,
    const float* __restrict__ rsum, const float* __restrict__ pgen,
    float* __restrict__ final)
{
    const int b = blockIdx.y;
    const int v0 = (blockIdx.x * 256 + threadIdx.x) << 2;
    if (v0 >= VX_) return;
    const float M = rmax[b];
    const float sc = pgen[b] / rsum[b];
    const float* row = logits + (long)b * V_;
    float* out = final + (long)b * VX_ + v0;
#pragma unroll
    for (int j = 0; j < 4; ++j) {
        const int v = v0 + j;
        if (v < VX_) out[j] = (v < V_) ? __expf(row[v] - M) * sc : 0.f;
    }
}

// scatter-add copy distribution
__global__ __launch_bounds__(256) void scatter_kernel(
    const int* __restrict__ ids, const float* __restrict__ attn,
    const float* __restrict__ pgen, float* __restrict__ final)
{
    const int s = blockIdx.x * 256 + threadIdx.x;
    const int b = blockIdx.y;
    if (s < 400) {
        const float v = (1.0f - pgen[b]) * attn[b * 400 + s];
        atomicAdd(final + (long)b * VX_ + ids[b * 400 + s], v);
    }
}

extern "C" void kernel_launch(void* const* d_in, const int* in_sizes, int n_in,
                              void* d_out, int out_size, void* d_ws, size_t ws_size,
                              hipStream_t stream)
{
    const float* input_emb  = (const float*)d_in[0];
    const float* input_feed = (const float*)d_in[1];
    const float* hidden     = (const float*)d_in[2];
    const float* context    = (const float*)d_in[3];
    const float* states     = (const float*)d_in[4];
    const float* sfeat      = (const float*)d_in[5];
    const float* mask       = (const float*)d_in[6];
    const float* cov        = (const float*)d_in[7];
    const int*   src_ids    = (const int*)d_in[8];
    const float* W_ic  = (const float*)d_in[9];
    const float* b_ic  = (const float*)d_in[10];
    const float* W_ih  = (const float*)d_in[11];
    const float* W_hh  = (const float*)d_in[12];
    const float* b_ih  = (const float*)d_in[13];
    const float* b_hh  = (const float*)d_in[14];
    const float* W_dec = (const float*)d_in[15];
    const float* b_att = (const float*)d_in[16];
    const float* v_att = (const float*)d_in[17];
    const float* w_c   = (const float*)d_in[18];
    const float* W_out = (const float*)d_in[19];
    const float* b_out = (const float*)d_in[20];
    const float* W_pg  = (const float*)d_in[21];
    const float* b_pg  = (const float*)d_in[22];
    const float* W_v   = (const float*)d_in[23];
    const float* b_v   = (const float*)d_in[24];

    float* out = (float*)d_out;
    float* o_final = out + OFF_FINAL;
    float* o_pgen  = out + OFF_PGEN;
    float* o_attn  = out + OFF_ATTN;
    float* o_cov   = out + OFF_COV;
    float* o_h1    = out + OFF_H1;
    float* o_c1    = out + OFF_C1;
    float* o_dec   = out + OFF_DEC;

    float* ws = (float*)d_ws;
    float* w_x      = ws;            // 128*512
    float* w_gates  = ws + 65536;    // 128*2048
    float* w_decfea = ws + 327680;   // 128*512
    float* w_e      = ws + 393216;   // 128*400
    float* w_ctx    = ws + 444416;   // 128*512
    float* w_logits = ws + 509952;   // 128*50257
    float* w_rmax   = ws + 6942848;  // 128
    float* w_rsum   = ws + 6942976;  // 128

    const dim3 blk(256);
    // x = [emb, feed] @ W_ic^T + b_ic      (one dual-phase MFMA GEMM)
    gemm_mfma<<<8, blk, 0, stream>>>(input_emb, W_ic, 1024, 0,
                                     input_feed, W_ic, 1024, 512,
                                     b_ic, nullptr, w_x, 512);
    // gates = x @ W_ih^T + h0 @ W_hh^T + b_ih + b_hh
    gemm_mfma<<<32, blk, 0, stream>>>(w_x, W_ih, 512, 0,
                                      hidden, W_hh, 512, 0,
                                      b_ih, b_hh, w_gates, 2048);
    lstm_cell<<<256, blk, 0, stream>>>(w_gates, context, o_h1, o_c1);
    // dec_fea = h1 @ W_dec^T + b_att
    gemm_mfma<<<8, blk, 0, stream>>>(o_h1, W_dec, 512, 0,
                                     nullptr, nullptr, 0, 0,
                                     b_att, nullptr, w_decfea, 512);
    // attention
    attn_scores<<<12800, blk, 0, stream>>>(sfeat, w_decfea, cov, w_c, v_att, w_e);
    attn_softmax<<<128, blk, 0, stream>>>(w_e, mask, cov, o_attn, o_cov, w_ctx);
    ctx_kernel<<<512, blk, 0, stream>>>(o_attn, states, w_ctx);
    // dec_out = [h1, ctx] @ W_out^T + b_out
    gemm_mfma<<<8, blk, 0, stream>>>(o_h1, W_out, 1024, 0,
                                     w_ctx, W_out, 1024, 512,
                                     b_out, nullptr, o_dec, 512);
    pgen_kernel<<<128, dim3(64), 0, stream>>>(o_dec, W_pg, b_pg, o_pgen);
    // vocab logits + softmax + final distribution
    gemm_mfma<<<786, blk, 0, stream>>>(o_dec, W_v, 512, 0,
                                       nullptr, nullptr, 0, 0,
                                       b_v, nullptr, w_logits, 50257);
    row_stats<<<128, blk, 0, stream>>>(w_logits, w_rmax, w_rsum);
    final_write<<<dim3(50, 128), blk, 0, stream>>>(w_logits, w_rmax, w_rsum, o_pgen, o_final);
    scatter_kernel<<<dim3(2, 128), blk, 0, stream>>>(src_ids, o_attn, o_pgen, o_final);
}

// Round 3
// 521.817 us; speedup vs baseline: 1.8044x; 1.1817x over previous
//
#include <hip/hip_runtime.h>
#include <hip/hip_bf16.h>

// Shapes
#define B_   128
#define S_   400
#define H_   512
#define V_   50257
#define VX_  50307

// Output offsets (floats, concatenated in return order)
#define OFF_FINAL 0
#define OFF_PGEN  6439296
#define OFF_ATTN  6439424
#define OFF_COV   6490624
#define OFF_H1    6541824
#define OFF_C1    6607360
#define OFF_DEC   6672896

typedef __attribute__((ext_vector_type(8))) short bf16x8;
typedef __attribute__((ext_vector_type(4))) float f32x4;

static __device__ __forceinline__ float sigmoid_f(float x) {
    return 1.0f / (1.0f + __expf(-x));
}
static __device__ __forceinline__ float tanh_f(float x) {
    return 1.0f - 2.0f / (__expf(2.0f * x) + 1.0f);
}
// f32x2 -> packed bf16x2 (RNE) — v_cvt_pk_bf16_f32 on gfx950
static __device__ __forceinline__ unsigned int pk2(float x, float y) {
    union { __hip_bfloat162 h; unsigned int u; } cv;
    cv.h = __float22bfloat162_rn(make_float2(x, y));
    return cv.u;
}

// ---------------------------------------------------------------------------
// C[128 x N] = A1[128x512] @ W1^T + (A2 ? A2[128x512] @ W2^T : 0) + bias1 (+bias2)
// bf16 MFMA 16x16x32, tile M=128 x N=NT*16, BK=32, 256 threads (4 waves).
// Register-prefetch pipeline: global loads for step s+1 issued before MFMAs of
// step s, so HBM latency overlaps compute instead of serializing each K-step.
// LDS rows padded 32->40 bf16.
// ---------------------------------------------------------------------------
template <int NT>
__global__ __launch_bounds__(256) void gemm_mfma(
    const float* __restrict__ A1, const float* __restrict__ W1, int ldw1, int kwo1,
    const float* __restrict__ A2, const float* __restrict__ W2, int ldw2, int kwo2,
    const float* __restrict__ bias1, const float* __restrict__ bias2,
    float* __restrict__ C, int N)
{
    __shared__ __align__(16) unsigned short As[128 * 40];
    __shared__ __align__(16) unsigned short Ws[NT * 16 * 40];
    const int tid  = threadIdx.x;
    const int bn0  = blockIdx.x * (NT * 16);
    const int lane = tid & 63;
    const int wv   = tid >> 6;     // wave 0..3 -> m-range wv*32
    const int quad = lane >> 4;    // 0..3
    const int col  = lane & 15;

    f32x4 acc[2][NT];
#pragma unroll
    for (int i = 0; i < 2; ++i)
#pragma unroll
        for (int j = 0; j < NT; ++j) acc[i][j] = (f32x4){0.f, 0.f, 0.f, 0.f};

    // staging assignment: A 128x32 -> 16 floats/thread; W (NT*16)x32 -> NT*2 floats
    const int ar = tid >> 1;
    const int ac = (tid & 1) << 4;
    const int wr = (NT == 8) ? (tid >> 1) : (tid >> 2);
    const int wc = (NT == 8) ? ((tid & 1) << 4) : ((tid & 3) << 3);
    const int wrg = (bn0 + wr < N) ? (bn0 + wr) : (N - 1);

    const int nph = (A2 != nullptr) ? 2 : 1;
    const int nsteps = nph << 4;
    const float* ApB[2];
    const float* WpB[2];
    ApB[0] = A1 + (long)ar * 512 + ac;
    WpB[0] = W1 + (long)wrg * ldw1 + kwo1 + wc;
    ApB[1] = A2 ? (A2 + (long)ar * 512 + ac) : ApB[0];
    WpB[1] = W2 ? (W2 + (long)wrg * ldw2 + kwo2 + wc) : WpB[0];

    float4 aC[4], wC[NT / 2], aN[4], wN[NT / 2];

    // fetch step s into (a, w)
    auto fetch = [&](int s, float4* a, float4* w) {
        const int ph = s >> 4;
        const int k0 = (s & 15) << 5;
        const float* Ap = ApB[ph] + k0;
        const float* Wp = WpB[ph] + k0;
#pragma unroll
        for (int i = 0; i < 4; ++i) a[i] = *(const float4*)(Ap + i * 4);
#pragma unroll
        for (int i = 0; i < NT / 2; ++i) w[i] = *(const float4*)(Wp + i * 4);
    };

    fetch(0, aC, wC);
    for (int s = 0; s < nsteps; ++s) {
        __syncthreads();  // previous iter's LDS frag reads complete
        uint4* apd = (uint4*)&As[ar * 40 + ac];
        apd[0] = make_uint4(pk2(aC[0].x, aC[0].y), pk2(aC[0].z, aC[0].w),
                            pk2(aC[1].x, aC[1].y), pk2(aC[1].z, aC[1].w));
        apd[1] = make_uint4(pk2(aC[2].x, aC[2].y), pk2(aC[2].z, aC[2].w),
                            pk2(aC[3].x, aC[3].y), pk2(aC[3].z, aC[3].w));
        uint4* wpd = (uint4*)&Ws[wr * 40 + wc];
        wpd[0] = make_uint4(pk2(wC[0].x, wC[0].y), pk2(wC[0].z, wC[0].w),
                            pk2(wC[1].x, wC[1].y), pk2(wC[1].z, wC[1].w));
        if (NT == 8)
            wpd[1] = make_uint4(pk2(wC[2].x, wC[2].y), pk2(wC[2].z, wC[2].w),
                                pk2(wC[3].x, wC[3].y), pk2(wC[3].z, wC[3].w));
        __syncthreads();

        if (s + 1 < nsteps) fetch(s + 1, aN, wN);  // overlap with MFMAs below

        const bf16x8 aF0 = *(const bf16x8*)&As[(wv * 32 + col) * 40 + quad * 8];
        const bf16x8 aF1 = *(const bf16x8*)&As[(wv * 32 + 16 + col) * 40 + quad * 8];
#pragma unroll
        for (int ni = 0; ni < NT; ++ni) {
            const bf16x8 bF = *(const bf16x8*)&Ws[(ni * 16 + col) * 40 + quad * 8];
            acc[0][ni] = __builtin_amdgcn_mfma_f32_16x16x32_bf16(aF0, bF, acc[0][ni], 0, 0, 0);
            acc[1][ni] = __builtin_amdgcn_mfma_f32_16x16x32_bf16(aF1, bF, acc[1][ni], 0, 0, 0);
        }
#pragma unroll
        for (int i = 0; i < 4; ++i) aC[i] = aN[i];
#pragma unroll
        for (int i = 0; i < NT / 2; ++i) wC[i] = wN[i];
    }

    // epilogue: C/D layout col=lane&15, row=quad*4+reg
#pragma unroll
    for (int mi = 0; mi < 2; ++mi) {
#pragma unroll
        for (int ni = 0; ni < NT; ++ni) {
            const int n = bn0 + ni * 16 + col;
            if (n < N) {
                float bv = bias1[n];
                if (bias2) bv += bias2[n];
#pragma unroll
                for (int r = 0; r < 4; ++r) {
                    const int m = wv * 32 + mi * 16 + quad * 4 + r;
                    C[(long)m * N + n] = acc[mi][ni][r] + bv;
                }
            }
        }
    }
}

// LSTM cell elementwise: gates (B x 2048) -> h1, c1 (B x 512)
__global__ __launch_bounds__(256) void lstm_cell(
    const float* __restrict__ gates, const float* __restrict__ c0,
    float* __restrict__ h1, float* __restrict__ c1)
{
    const int idx = blockIdx.x * 256 + threadIdx.x;  // 65536
    const int b = idx >> 9, h = idx & 511;
    const float* g = gates + ((long)b << 11);
    const float gi = sigmoid_f(g[h]);
    const float gf = sigmoid_f(g[h + 512]);
    const float gg = tanh_f(g[h + 1024]);
    const float go = sigmoid_f(g[h + 1536]);
    const float c = gf * c0[idx] + gi * gg;
    c1[idx] = c;
    h1[idx] = go * tanh_f(c);
}

// e[b,s] = sum_h tanh(sf[b,s,h] + dec_fea[b,h] + wc*cov[b,s]) * v_att[h]
__global__ __launch_bounds__(256) void attn_scores(
    const float* __restrict__ sfeat, const float* __restrict__ decfea,
    const float* __restrict__ cov, const float* __restrict__ wc,
    const float* __restrict__ vatt, float* __restrict__ e)
{
    const int lane = threadIdx.x & 63;
    const int pair = blockIdx.x * 4 + (threadIdx.x >> 6);  // b*400+s
    const int b = pair / 400;
    const float cc = wc[0] * cov[pair];
    const float* sp = sfeat + ((long)pair << 9) + (lane << 3);
    const float* dp = decfea + (b << 9) + (lane << 3);
    const float* vp = vatt + (lane << 3);
    const float4 s0 = *(const float4*)sp, s1 = *(const float4*)(sp + 4);
    const float4 d0 = *(const float4*)dp, d1 = *(const float4*)(dp + 4);
    const float4 v0 = *(const float4*)vp, v1 = *(const float4*)(vp + 4);
    float acc = tanh_f(s0.x + d0.x + cc) * v0.x
              + tanh_f(s0.y + d0.y + cc) * v0.y
              + tanh_f(s0.z + d0.z + cc) * v0.z
              + tanh_f(s0.w + d0.w + cc) * v0.w
              + tanh_f(s1.x + d1.x + cc) * v1.x
              + tanh_f(s1.y + d1.y + cc) * v1.y
              + tanh_f(s1.z + d1.z + cc) * v1.z
              + tanh_f(s1.w + d1.w + cc) * v1.w;
#pragma unroll
    for (int off = 32; off > 0; off >>= 1) acc += __shfl_down(acc, off);
    if (lane == 0) e[pair] = acc;
}

// Masked softmax over S per batch row + coverage update; also zeroes ctx accum.
__global__ __launch_bounds__(256) void attn_softmax(
    const float* __restrict__ e, const float* __restrict__ mask,
    const float* __restrict__ cov,
    float* __restrict__ attn, float* __restrict__ covnew, float* __restrict__ ctx)
{
    __shared__ float sm[4], sps[4], spms[4];
    const int b = blockIdx.x, tid = threadIdx.x;
    ctx[(b << 9) + tid] = 0.f;
    ctx[(b << 9) + 256 + tid] = 0.f;

    float vals[2], msk[2];
    float m = -3.0e38f;
#pragma unroll
    for (int it = 0; it < 2; ++it) {
        const int s = tid + (it << 8);
        float mk = 0.f, v = -3.0e38f;
        if (s < 400) {
            mk = mask[b * 400 + s];
            v = (mk > 0.f) ? e[b * 400 + s] : -1.0e9f;
        }
        vals[it] = v; msk[it] = mk;
        m = fmaxf(m, v);
    }
#pragma unroll
    for (int off = 32; off > 0; off >>= 1) m = fmaxf(m, __shfl_down(m, off));
    if ((tid & 63) == 0) sm[tid >> 6] = m;
    __syncthreads();
    const float M = fmaxf(fmaxf(sm[0], sm[1]), fmaxf(sm[2], sm[3]));

    float p[2], sp = 0.f, spm = 0.f;
#pragma unroll
    for (int it = 0; it < 2; ++it) {
        const int s = tid + (it << 8);
        float pv = 0.f;
        if (s < 400) pv = __expf(vals[it] - M);
        p[it] = pv; sp += pv; spm += pv * msk[it];
    }
#pragma unroll
    for (int off = 32; off > 0; off >>= 1) {
        sp += __shfl_down(sp, off);
        spm += __shfl_down(spm, off);
    }
    if ((tid & 63) == 0) { sps[tid >> 6] = sp; spms[tid >> 6] = spm; }
    __syncthreads();
    const float SP = sps[0] + sps[1] + sps[2] + sps[3];
    const float SPM = spms[0] + spms[1] + spms[2] + spms[3];
    const float inv = 1.0f / (SPM + 1e-12f * SP);
#pragma unroll
    for (int it = 0; it < 2; ++it) {
        const int s = tid + (it << 8);
        if (s < 400) {
            const float a = p[it] * msk[it] * inv;
            attn[b * 400 + s] = a;
            covnew[b * 400 + s] = cov[b * 400 + s] + a;
        }
    }
}

// ctx[b,h] += sum over an s-chunk of attn[b,s]*states[b,s,h]; 4 chunks per b
__global__ __launch_bounds__(256) void ctx_kernel(
    const float* __restrict__ attn, const float* __restrict__ states,
    float* __restrict__ ctx)
{
    const int bx = blockIdx.x;  // 512
    const int b = bx >> 2, chunk = bx & 3;
    const int tid = threadIdx.x;
    const int c = tid & 127;
    const int sh = tid >> 7;
    const int s0 = chunk * 100 + sh;
    const float* base = states + (long)b * 400 * 512;
    float4 acc = make_float4(0.f, 0.f, 0.f, 0.f);
    for (int i = 0; i < 50; ++i) {
        const int s = s0 + (i << 1);
        const float a = attn[b * 400 + s];
        const float4 st = *(const float4*)(base + (long)s * 512 + (c << 2));
        acc.x = fmaf(a, st.x, acc.x);
        acc.y = fmaf(a, st.y, acc.y);
        acc.z = fmaf(a, st.z, acc.z);
        acc.w = fmaf(a, st.w, acc.w);
    }
    float* cp = ctx + (b << 9) + (c << 2);
    atomicAdd(cp + 0, acc.x);
    atomicAdd(cp + 1, acc.y);
    atomicAdd(cp + 2, acc.z);
    atomicAdd(cp + 3, acc.w);
}

// p_gen[b] = sigmoid(dec_out[b,:]·W_pg + b_pg)
__global__ __launch_bounds__(64) void pgen_kernel(
    const float* __restrict__ dec_out, const float* __restrict__ wpg,
    const float* __restrict__ bpg, float* __restrict__ pgen)
{
    const int b = blockIdx.x, lane = threadIdx.x;
    const float* dp = dec_out + (b << 9) + (lane << 3);
    const float* wp = wpg + (lane << 3);
    const float4 d0 = *(const float4*)dp, d1 = *(const float4*)(dp + 4);
    const float4 w0 = *(const float4*)wp, w1 = *(const float4*)(wp + 4);
    float acc = d0.x * w0.x + d0.y * w0.y + d0.z * w0.z + d0.w * w0.w
              + d1.x * w1.x + d1.y * w1.y + d1.z * w1.z + d1.w * w1.w;
#pragma unroll
    for (int off = 32; off > 0; off >>= 1) acc += __shfl_down(acc, off);
    if (lane == 0) pgen[b] = sigmoid_f(acc + bpg[0]);
}

// stage 1: per-(row, chunk) max & exp-sum partials. grid (8, 128).
__global__ __launch_bounds__(256) void row_stats_part(
    const float* __restrict__ logits, float* __restrict__ pm, float* __restrict__ ps)
{
    __shared__ float sred[4];
    const int b = blockIdx.y, cx = blockIdx.x, tid = threadIdx.x;
    const int v0 = cx * 6283;
    const int v1 = (v0 + 6283 < V_) ? (v0 + 6283) : V_;
    const float* row = logits + (long)b * V_;

    float m = -3.0e38f;
    for (int v = v0 + tid; v < v1; v += 256) m = fmaxf(m, row[v]);
#pragma unroll
    for (int off = 32; off > 0; off >>= 1) m = fmaxf(m, __shfl_down(m, off));
    if ((tid & 63) == 0) sred[tid >> 6] = m;
    __syncthreads();
    const float M = fmaxf(fmaxf(sred[0], sred[1]), fmaxf(sred[2], sred[3]));
    __syncthreads();

    float s = 0.f;
    for (int v = v0 + tid; v < v1; v += 256) s += __expf(row[v] - M);
#pragma unroll
    for (int off = 32; off > 0; off >>= 1) s += __shfl_down(s, off);
    if ((tid & 63) == 0) sred[tid >> 6] = s;
    __syncthreads();
    if (tid == 0) {
        pm[b * 8 + cx] = M;
        ps[b * 8 + cx] = sred[0] + sred[1] + sred[2] + sred[3];
    }
}

// stage 2: merge 8 partials per row. 1 block x 128 threads.
__global__ __launch_bounds__(128) void row_stats_fin(
    const float* __restrict__ pm, const float* __restrict__ ps,
    float* __restrict__ rmax, float* __restrict__ rsum)
{
    const int b = threadIdx.x;
    float M = -3.0e38f;
#pragma unroll
    for (int i = 0; i < 8; ++i) M = fmaxf(M, pm[b * 8 + i]);
    float S = 0.f;
#pragma unroll
    for (int i = 0; i < 8; ++i) S += ps[b * 8 + i] * __expf(pm[b * 8 + i] - M);
    rmax[b] = M;
    rsum[b] = S;
}

// final[b, v<V] = p_gen*softmax(logits); final[b, V..VEXT) = 0
__global__ __launch_bounds__(256) void final_write(
    const float* __restrict__ logits, const float* __restrict__ rmax,
    const float* __restrict__ rsum, const float* __restrict__ pgen,
    float* __restrict__ final)
{
    const int b = blockIdx.y;
    const int v0 = (blockIdx.x * 256 + threadIdx.x) << 2;
    if (v0 >= VX_) return;
    const float M = rmax[b];
    const float sc = pgen[b] / rsum[b];
    const float* row = logits + (long)b * V_;
    float* out = final + (long)b * VX_ + v0;
#pragma unroll
    for (int j = 0; j < 4; ++j) {
        const int v = v0 + j;
        if (v < VX_) out[j] = (v < V_) ? __expf(row[v] - M) * sc : 0.f;
    }
}

// scatter-add copy distribution
__global__ __launch_bounds__(256) void scatter_kernel(
    const int* __restrict__ ids, const float* __restrict__ attn,
    const float* __restrict__ pgen, float* __restrict__ final)
{
    const int s = blockIdx.x * 256 + threadIdx.x;
    const int b = blockIdx.y;
    if (s < 400) {
        const float v = (1.0f - pgen[b]) * attn[b * 400 + s];
        atomicAdd(final + (long)b * VX_ + ids[b * 400 + s], v);
    }
}

extern "C" void kernel_launch(void* const* d_in, const int* in_sizes, int n_in,
                              void* d_out, int out_size, void* d_ws, size_t ws_size,
                              hipStream_t stream)
{
    const float* input_emb  = (const float*)d_in[0];
    const float* input_feed = (const float*)d_in[1];
    const float* hidden     = (const float*)d_in[2];
    const float* context    = (const float*)d_in[3];
    const float* states     = (const float*)d_in[4];
    const float* sfeat      = (const float*)d_in[5];
    const float* mask       = (const float*)d_in[6];
    const float* cov        = (const float*)d_in[7];
    const int*   src_ids    = (const int*)d_in[8];
    const float* W_ic  = (const float*)d_in[9];
    const float* b_ic  = (const float*)d_in[10];
    const float* W_ih  = (const float*)d_in[11];
    const float* W_hh  = (const float*)d_in[12];
    const float* b_ih  = (const float*)d_in[13];
    const float* b_hh  = (const float*)d_in[14];
    const float* W_dec = (const float*)d_in[15];
    const float* b_att = (const float*)d_in[16];
    const float* v_att = (const float*)d_in[17];
    const float* w_c   = (const float*)d_in[18];
    const float* W_out = (const float*)d_in[19];
    const float* b_out = (const float*)d_in[20];
    const float* W_pg  = (const float*)d_in[21];
    const float* b_pg  = (const float*)d_in[22];
    const float* W_v   = (const float*)d_in[23];
    const float* b_v   = (const float*)d_in[24];

    float* out = (float*)d_out;
    float* o_final = out + OFF_FINAL;
    float* o_pgen  = out + OFF_PGEN;
    float* o_attn  = out + OFF_ATTN;
    float* o_cov   = out + OFF_COV;
    float* o_h1    = out + OFF_H1;
    float* o_c1    = out + OFF_C1;
    float* o_dec   = out + OFF_DEC;

    float* ws = (float*)d_ws;
    float* w_x      = ws;            // 128*512
    float* w_gates  = ws + 65536;    // 128*2048
    float* w_decfea = ws + 327680;   // 128*512
    float* w_e      = ws + 393216;   // 128*400
    float* w_ctx    = ws + 444416;   // 128*512
    float* w_logits = ws + 509952;   // 128*50257
    float* w_rmax   = ws + 6942848;  // 128
    float* w_rsum   = ws + 6942976;  // 128
    float* w_pm     = ws + 6943104;  // 1024
    float* w_ps     = ws + 6944128;  // 1024

    const dim3 blk(256);
    // x = [emb, feed] @ W_ic^T + b_ic      (one dual-phase MFMA GEMM)
    gemm_mfma<4><<<8, blk, 0, stream>>>(input_emb, W_ic, 1024, 0,
                                        input_feed, W_ic, 1024, 512,
                                        b_ic, nullptr, w_x, 512);
    // gates = x @ W_ih^T + h0 @ W_hh^T + b_ih + b_hh
    gemm_mfma<4><<<32, blk, 0, stream>>>(w_x, W_ih, 512, 0,
                                         hidden, W_hh, 512, 0,
                                         b_ih, b_hh, w_gates, 2048);
    lstm_cell<<<256, blk, 0, stream>>>(w_gates, context, o_h1, o_c1);
    // dec_fea = h1 @ W_dec^T + b_att
    gemm_mfma<4><<<8, blk, 0, stream>>>(o_h1, W_dec, 512, 0,
                                        nullptr, nullptr, 0, 0,
                                        b_att, nullptr, w_decfea, 512);
    // attention
    attn_scores<<<12800, blk, 0, stream>>>(sfeat, w_decfea, cov, w_c, v_att, w_e);
    attn_softmax<<<128, blk, 0, stream>>>(w_e, mask, cov, o_attn, o_cov, w_ctx);
    ctx_kernel<<<512, blk, 0, stream>>>(o_attn, states, w_ctx);
    // dec_out = [h1, ctx] @ W_out^T + b_out
    gemm_mfma<4><<<8, blk, 0, stream>>>(o_h1, W_out, 1024, 0,
                                        w_ctx, W_out, 1024, 512,
                                        b_out, nullptr, o_dec, 512);
    pgen_kernel<<<128, dim3(64), 0, stream>>>(o_dec, W_pg, b_pg, o_pgen);
    // vocab logits + softmax + final distribution
    gemm_mfma<8><<<393, blk, 0, stream>>>(o_dec, W_v, 512, 0,
                                          nullptr, nullptr, 0, 0,
                                          b_v, nullptr, w_logits, 50257);
    row_stats_part<<<dim3(8, 128), blk, 0, stream>>>(w_logits, w_pm, w_ps);
    row_stats_fin<<<1, dim3(128), 0, stream>>>(w_pm, w_ps, w_rmax, w_rsum);
    final_write<<<dim3(50, 128), blk, 0, stream>>>(w_logits, w_rmax, w_rsum, o_pgen, o_final);
    scatter_kernel<<<dim3(2, 128), blk, 0, stream>>>(src_ids, o_attn, o_pgen, o_final);
}

// Round 4
// 492.094 us; speedup vs baseline: 1.9134x; 1.0604x over previous
//
#include <hip/hip_runtime.h>
#include <hip/hip_bf16.h>

// Shapes
#define B_   128
#define S_   400
#define H_   512
#define V_   50257
#define VX_  50307

// Output offsets (floats, concatenated in return order)
#define OFF_FINAL 0
#define OFF_PGEN  6439296
#define OFF_ATTN  6439424
#define OFF_COV   6490624
#define OFF_H1    6541824
#define OFF_C1    6607360
#define OFF_DEC   6672896

typedef __attribute__((ext_vector_type(8))) short bf16x8;
typedef __attribute__((ext_vector_type(4))) float f32x4;

static __device__ __forceinline__ float sigmoid_f(float x) {
    return 1.0f / (1.0f + __expf(-x));
}
static __device__ __forceinline__ float tanh_f(float x) {
    return 1.0f - 2.0f / (__expf(2.0f * x) + 1.0f);
}
// f32x2 -> packed bf16x2 (RNE) — v_cvt_pk_bf16_f32 on gfx950
static __device__ __forceinline__ unsigned int pk2(float x, float y) {
    union { __hip_bfloat162 h; unsigned int u; } cv;
    cv.h = __float22bfloat162_rn(make_float2(x, y));
    return cv.u;
}

// zero the split-K accumulation buffers (+ pgen accumulator)
__global__ __launch_bounds__(256) void zero_bufs(
    float* __restrict__ a, float* __restrict__ b, float* __restrict__ c,
    float* __restrict__ d)
{
    const int i = blockIdx.x * 256 + threadIdx.x;  // 65536
    a[i] = 0.f; b[i] = 0.f; c[i] = 0.f;
    if (i < 128) d[i] = 0.f;
}

// ---------------------------------------------------------------------------
// C[128 x N] (+)= A1[128x512] @ W1^T + (A2 ? A2[128x512] @ W2^T : 0) + bias1
// Split-K: grid.y = K-chunks; chunk c covers kg in [c*KC, (c+1)*KC), KC=Ktot/chunks.
// gridDim.y>1 -> atomicAdd epilogue into pre-zeroed C (bias added by chunk 0);
// gridDim.y==1 -> direct store. Optional fused p_gen partial dot (wpg != null).
// bf16 MFMA 16x16x32, tile M=128 x N=NT*16, BK=32, 256 thr, reg-prefetch pipeline.
// ---------------------------------------------------------------------------
template <int NT>
__global__ __launch_bounds__(256) void gemm_mfma(
    const float* __restrict__ A1, const float* __restrict__ W1, int ldw1, int kwo1,
    const float* __restrict__ A2, const float* __restrict__ W2, int ldw2, int kwo2,
    const float* __restrict__ bias1,
    float* __restrict__ C, int N,
    const float* __restrict__ wpg, float* __restrict__ pgen_acc)
{
    __shared__ __align__(16) unsigned short As[128 * 40];
    __shared__ __align__(16) unsigned short Ws[NT * 16 * 40];
    const int tid  = threadIdx.x;
    const int bn0  = blockIdx.x * (NT * 16);
    const int lane = tid & 63;
    const int wv   = tid >> 6;
    const int quad = lane >> 4;
    const int col  = lane & 15;

    f32x4 acc[2][NT];
#pragma unroll
    for (int i = 0; i < 2; ++i)
#pragma unroll
        for (int j = 0; j < NT; ++j) acc[i][j] = (f32x4){0.f, 0.f, 0.f, 0.f};

    const int ar = tid >> 1;
    const int ac = (tid & 1) << 4;
    const int wr = (NT == 8) ? (tid >> 1) : (tid >> 2);
    const int wc = (NT == 8) ? ((tid & 1) << 4) : ((tid & 3) << 3);
    const int wrg = (bn0 + wr < N) ? (bn0 + wr) : (N - 1);

    const int Ktot = (A2 != nullptr) ? 1024 : 512;
    const int KC   = Ktot / gridDim.y;
    const int kg0  = blockIdx.y * KC;
    const int nsteps = KC >> 5;

    const float* ApB[2];
    const float* WpB[2];
    ApB[0] = A1 + (long)ar * 512 + ac;
    WpB[0] = W1 + (long)wrg * ldw1 + kwo1 + wc;
    ApB[1] = A2 ? (A2 + (long)ar * 512 + ac) : ApB[0];
    WpB[1] = W2 ? (W2 + (long)wrg * ldw2 + kwo2 + wc) : WpB[0];

    float4 aC[4], wC[NT / 2], aN[4], wN[NT / 2];

    auto fetch = [&](int s, float4* a, float4* w) {
        const int kg = kg0 + (s << 5);
        const int ph = kg >> 9;
        const int k0 = kg & 511;
        const float* Ap = ApB[ph] + k0;
        const float* Wp = WpB[ph] + k0;
#pragma unroll
        for (int i = 0; i < 4; ++i) a[i] = *(const float4*)(Ap + i * 4);
#pragma unroll
        for (int i = 0; i < NT / 2; ++i) w[i] = *(const float4*)(Wp + i * 4);
    };

    fetch(0, aC, wC);
    for (int s = 0; s < nsteps; ++s) {
        __syncthreads();
        uint4* apd = (uint4*)&As[ar * 40 + ac];
        apd[0] = make_uint4(pk2(aC[0].x, aC[0].y), pk2(aC[0].z, aC[0].w),
                            pk2(aC[1].x, aC[1].y), pk2(aC[1].z, aC[1].w));
        apd[1] = make_uint4(pk2(aC[2].x, aC[2].y), pk2(aC[2].z, aC[2].w),
                            pk2(aC[3].x, aC[3].y), pk2(aC[3].z, aC[3].w));
        uint4* wpd = (uint4*)&Ws[wr * 40 + wc];
        wpd[0] = make_uint4(pk2(wC[0].x, wC[0].y), pk2(wC[0].z, wC[0].w),
                            pk2(wC[1].x, wC[1].y), pk2(wC[1].z, wC[1].w));
        if (NT == 8)
            wpd[1] = make_uint4(pk2(wC[2].x, wC[2].y), pk2(wC[2].z, wC[2].w),
                                pk2(wC[3].x, wC[3].y), pk2(wC[3].z, wC[3].w));
        __syncthreads();

        if (s + 1 < nsteps) fetch(s + 1, aN, wN);

        const bf16x8 aF0 = *(const bf16x8*)&As[(wv * 32 + col) * 40 + quad * 8];
        const bf16x8 aF1 = *(const bf16x8*)&As[(wv * 32 + 16 + col) * 40 + quad * 8];
#pragma unroll
        for (int ni = 0; ni < NT; ++ni) {
            const bf16x8 bF = *(const bf16x8*)&Ws[(ni * 16 + col) * 40 + quad * 8];
            acc[0][ni] = __builtin_amdgcn_mfma_f32_16x16x32_bf16(aF0, bF, acc[0][ni], 0, 0, 0);
            acc[1][ni] = __builtin_amdgcn_mfma_f32_16x16x32_bf16(aF1, bF, acc[1][ni], 0, 0, 0);
        }
#pragma unroll
        for (int i = 0; i < 4; ++i) aC[i] = aN[i];
#pragma unroll
        for (int i = 0; i < NT / 2; ++i) wC[i] = wN[i];
    }

    const bool split = (gridDim.y > 1);
    const bool addb  = (!split) || (blockIdx.y == 0);
    float pgp[2][4];
#pragma unroll
    for (int i = 0; i < 2; ++i)
#pragma unroll
        for (int r = 0; r < 4; ++r) pgp[i][r] = 0.f;

#pragma unroll
    for (int mi = 0; mi < 2; ++mi) {
#pragma unroll
        for (int ni = 0; ni < NT; ++ni) {
            const int n = bn0 + ni * 16 + col;
            if (n < N) {
                const float bv = addb ? bias1[n] : 0.f;
                const float wpv = wpg ? wpg[n] : 0.f;
#pragma unroll
                for (int r = 0; r < 4; ++r) {
                    const int m = wv * 32 + mi * 16 + quad * 4 + r;
                    const float v = acc[mi][ni][r] + bv;
                    if (split) atomicAdd(&C[(long)m * N + n], v);
                    else       C[(long)m * N + n] = v;
                    pgp[mi][r] += v * wpv;
                }
            }
        }
    }
    if (wpg) {
        // reduce over the 16 col-lanes of each quad, then one atomic per row
#pragma unroll
        for (int mi = 0; mi < 2; ++mi)
#pragma unroll
            for (int r = 0; r < 4; ++r) {
                float v = pgp[mi][r];
                v += __shfl_xor(v, 1); v += __shfl_xor(v, 2);
                v += __shfl_xor(v, 4); v += __shfl_xor(v, 8);
                if (col == 0) {
                    const int m = wv * 32 + mi * 16 + quad * 4 + r;
                    atomicAdd(&pgen_acc[m], v);
                }
            }
    }
}

// ---------------------------------------------------------------------------
// Fused gates GEMM + LSTM cell. grid 16 blocks x 32 h-cols.
// W rows quadrant-stacked (i,f,g,o for the block's 32 h-cols) so each thread
// holds all four gates of its (m,h) -> LSTM epilogue in-register.
// gates = x @ W_ih^T + h0 @ W_hh^T + b_ih + b_hh
// ---------------------------------------------------------------------------
__global__ __launch_bounds__(256) void gates_lstm(
    const float* __restrict__ x, const float* __restrict__ h0,
    const float* __restrict__ Wih, const float* __restrict__ Whh,
    const float* __restrict__ bih, const float* __restrict__ bhh,
    const float* __restrict__ c0,
    float* __restrict__ h1, float* __restrict__ c1)
{
    __shared__ __align__(16) unsigned short As[128 * 40];
    __shared__ __align__(16) unsigned short Ws[128 * 40];
    const int tid  = threadIdx.x;
    const int bh0  = blockIdx.x * 32;
    const int lane = tid & 63;
    const int wv   = tid >> 6;
    const int quad = lane >> 4;
    const int col  = lane & 15;

    f32x4 acc[2][8];
#pragma unroll
    for (int i = 0; i < 2; ++i)
#pragma unroll
        for (int j = 0; j < 8; ++j) acc[i][j] = (f32x4){0.f, 0.f, 0.f, 0.f};

    const int ar = tid >> 1;
    const int ac = (tid & 1) << 4;
    const int wr = tid >> 1;             // LDS W row 0..127 (4 quadrants x 32)
    const int wc = (tid & 1) << 4;
    const int wrow = ((wr >> 5) << 9) + bh0 + (wr & 31);  // global W row

    const float* ApB[2] = { x + (long)ar * 512 + ac, h0 + (long)ar * 512 + ac };
    const float* WpB[2] = { Wih + (long)wrow * 512 + wc, Whh + (long)wrow * 512 + wc };

    float4 aC[4], wC[4], aN[4], wN[4];
    auto fetch = [&](int s, float4* a, float4* w) {
        const int ph = s >> 4;
        const int k0 = (s & 15) << 5;
        const float* Ap = ApB[ph] + k0;
        const float* Wp = WpB[ph] + k0;
#pragma unroll
        for (int i = 0; i < 4; ++i) a[i] = *(const float4*)(Ap + i * 4);
#pragma unroll
        for (int i = 0; i < 4; ++i) w[i] = *(const float4*)(Wp + i * 4);
    };

    fetch(0, aC, wC);
    for (int s = 0; s < 32; ++s) {
        __syncthreads();
        uint4* apd = (uint4*)&As[ar * 40 + ac];
        apd[0] = make_uint4(pk2(aC[0].x, aC[0].y), pk2(aC[0].z, aC[0].w),
                            pk2(aC[1].x, aC[1].y), pk2(aC[1].z, aC[1].w));
        apd[1] = make_uint4(pk2(aC[2].x, aC[2].y), pk2(aC[2].z, aC[2].w),
                            pk2(aC[3].x, aC[3].y), pk2(aC[3].z, aC[3].w));
        uint4* wpd = (uint4*)&Ws[wr * 40 + wc];
        wpd[0] = make_uint4(pk2(wC[0].x, wC[0].y), pk2(wC[0].z, wC[0].w),
                            pk2(wC[1].x, wC[1].y), pk2(wC[1].z, wC[1].w));
        wpd[1] = make_uint4(pk2(wC[2].x, wC[2].y), pk2(wC[2].z, wC[2].w),
                            pk2(wC[3].x, wC[3].y), pk2(wC[3].z, wC[3].w));
        __syncthreads();

        if (s + 1 < 32) fetch(s + 1, aN, wN);

        const bf16x8 aF0 = *(const bf16x8*)&As[(wv * 32 + col) * 40 + quad * 8];
        const bf16x8 aF1 = *(const bf16x8*)&As[(wv * 32 + 16 + col) * 40 + quad * 8];
#pragma unroll
        for (int ni = 0; ni < 8; ++ni) {
            const bf16x8 bF = *(const bf16x8*)&Ws[(ni * 16 + col) * 40 + quad * 8];
            acc[0][ni] = __builtin_amdgcn_mfma_f32_16x16x32_bf16(aF0, bF, acc[0][ni], 0, 0, 0);
            acc[1][ni] = __builtin_amdgcn_mfma_f32_16x16x32_bf16(aF1, bF, acc[1][ni], 0, 0, 0);
        }
#pragma unroll
        for (int i = 0; i < 4; ++i) { aC[i] = aN[i]; wC[i] = wN[i]; }
    }

    // LSTM epilogue: n-tile ni covers LDS row ni*16+col -> gate q=ni>>1, par=ni&1
#pragma unroll
    for (int mi = 0; mi < 2; ++mi) {
#pragma unroll
        for (int par = 0; par < 2; ++par) {
            const int h = bh0 + par * 16 + col;
            const float bi = bih[h]        + bhh[h];
            const float bf = bih[512 + h]  + bhh[512 + h];
            const float bg = bih[1024 + h] + bhh[1024 + h];
            const float bo = bih[1536 + h] + bhh[1536 + h];
#pragma unroll
            for (int r = 0; r < 4; ++r) {
                const int m = wv * 32 + mi * 16 + quad * 4 + r;
                const float iv = sigmoid_f(acc[mi][par + 0][r] + bi);
                const float fv = sigmoid_f(acc[mi][par + 2][r] + bf);
                const float gv = tanh_f(acc[mi][par + 4][r] + bg);
                const float ov = sigmoid_f(acc[mi][par + 6][r] + bo);
                const float c = fv * c0[m * 512 + h] + iv * gv;
                c1[m * 512 + h] = c;
                h1[m * 512 + h] = ov * tanh_f(c);
            }
        }
    }
}

// e[b,s] = sum_h tanh(sf[b,s,h] + dec_fea[b,h] + wc*cov[b,s]) * v_att[h]
__global__ __launch_bounds__(256) void attn_scores(
    const float* __restrict__ sfeat, const float* __restrict__ decfea,
    const float* __restrict__ cov, const float* __restrict__ wc,
    const float* __restrict__ vatt, float* __restrict__ e)
{
    const int lane = threadIdx.x & 63;
    const int pair = blockIdx.x * 4 + (threadIdx.x >> 6);  // b*400+s
    const int b = pair / 400;
    const float cc = wc[0] * cov[pair];
    const float* sp = sfeat + ((long)pair << 9) + (lane << 3);
    const float* dp = decfea + (b << 9) + (lane << 3);
    const float* vp = vatt + (lane << 3);
    const float4 s0 = *(const float4*)sp, s1 = *(const float4*)(sp + 4);
    const float4 d0 = *(const float4*)dp, d1 = *(const float4*)(dp + 4);
    const float4 v0 = *(const float4*)vp, v1 = *(const float4*)(vp + 4);
    float acc = tanh_f(s0.x + d0.x + cc) * v0.x
              + tanh_f(s0.y + d0.y + cc) * v0.y
              + tanh_f(s0.z + d0.z + cc) * v0.z
              + tanh_f(s0.w + d0.w + cc) * v0.w
              + tanh_f(s1.x + d1.x + cc) * v1.x
              + tanh_f(s1.y + d1.y + cc) * v1.y
              + tanh_f(s1.z + d1.z + cc) * v1.z
              + tanh_f(s1.w + d1.w + cc) * v1.w;
#pragma unroll
    for (int off = 32; off > 0; off >>= 1) acc += __shfl_down(acc, off);
    if (lane == 0) e[pair] = acc;
}

// Masked softmax over S per batch row + coverage update; also zeroes ctx accum.
__global__ __launch_bounds__(256) void attn_softmax(
    const float* __restrict__ e, const float* __restrict__ mask,
    const float* __restrict__ cov,
    float* __restrict__ attn, float* __restrict__ covnew, float* __restrict__ ctx)
{
    __shared__ float sm[4], sps[4], spms[4];
    const int b = blockIdx.x, tid = threadIdx.x;
    ctx[(b << 9) + tid] = 0.f;
    ctx[(b << 9) + 256 + tid] = 0.f;

    float vals[2], msk[2];
    float m = -3.0e38f;
#pragma unroll
    for (int it = 0; it < 2; ++it) {
        const int s = tid + (it << 8);
        float mk = 0.f, v = -3.0e38f;
        if (s < 400) {
            mk = mask[b * 400 + s];
            v = (mk > 0.f) ? e[b * 400 + s] : -1.0e9f;
        }
        vals[it] = v; msk[it] = mk;
        m = fmaxf(m, v);
    }
#pragma unroll
    for (int off = 32; off > 0; off >>= 1) m = fmaxf(m, __shfl_down(m, off));
    if ((tid & 63) == 0) sm[tid >> 6] = m;
    __syncthreads();
    const float M = fmaxf(fmaxf(sm[0], sm[1]), fmaxf(sm[2], sm[3]));

    float p[2], sp = 0.f, spm = 0.f;
#pragma unroll
    for (int it = 0; it < 2; ++it) {
        const int s = tid + (it << 8);
        float pv = 0.f;
        if (s < 400) pv = __expf(vals[it] - M);
        p[it] = pv; sp += pv; spm += pv * msk[it];
    }
#pragma unroll
    for (int off = 32; off > 0; off >>= 1) {
        sp += __shfl_down(sp, off);
        spm += __shfl_down(spm, off);
    }
    if ((tid & 63) == 0) { sps[tid >> 6] = sp; spms[tid >> 6] = spm; }
    __syncthreads();
    const float SP = sps[0] + sps[1] + sps[2] + sps[3];
    const float SPM = spms[0] + spms[1] + spms[2] + spms[3];
    const float inv = 1.0f / (SPM + 1e-12f * SP);
#pragma unroll
    for (int it = 0; it < 2; ++it) {
        const int s = tid + (it << 8);
        if (s < 400) {
            const float a = p[it] * msk[it] * inv;
            attn[b * 400 + s] = a;
            covnew[b * 400 + s] = cov[b * 400 + s] + a;
        }
    }
}

// ctx[b,h] += sum over an s-chunk of attn[b,s]*states[b,s,h]; 4 chunks per b
__global__ __launch_bounds__(256) void ctx_kernel(
    const float* __restrict__ attn, const float* __restrict__ states,
    float* __restrict__ ctx)
{
    const int bx = blockIdx.x;  // 512
    const int b = bx >> 2, chunk = bx & 3;
    const int tid = threadIdx.x;
    const int c = tid & 127;
    const int sh = tid >> 7;
    const int s0 = chunk * 100 + sh;
    const float* base = states + (long)b * 400 * 512;
    float4 acc = make_float4(0.f, 0.f, 0.f, 0.f);
    for (int i = 0; i < 50; ++i) {
        const int s = s0 + (i << 1);
        const float a = attn[b * 400 + s];
        const float4 st = *(const float4*)(base + (long)s * 512 + (c << 2));
        acc.x = fmaf(a, st.x, acc.x);
        acc.y = fmaf(a, st.y, acc.y);
        acc.z = fmaf(a, st.z, acc.z);
        acc.w = fmaf(a, st.w, acc.w);
    }
    float* cp = ctx + (b << 9) + (c << 2);
    atomicAdd(cp + 0, acc.x);
    atomicAdd(cp + 1, acc.y);
    atomicAdd(cp + 2, acc.z);
    atomicAdd(cp + 3, acc.w);
}

// stage 1: per-(row, chunk) max & exp-sum partials. grid (8, 128).
__global__ __launch_bounds__(256) void row_stats_part(
    const float* __restrict__ logits, float* __restrict__ pm, float* __restrict__ ps)
{
    __shared__ float sred[4];
    const int b = blockIdx.y, cx = blockIdx.x, tid = threadIdx.x;
    const int v0 = cx * 6283;
    const int v1 = (v0 + 6283 < V_) ? (v0 + 6283) : V_;
    const float* row = logits + (long)b * V_;

    float m = -3.0e38f;
    for (int v = v0 + tid; v < v1; v += 256) m = fmaxf(m, row[v]);
#pragma unroll
    for (int off = 32; off > 0; off >>= 1) m = fmaxf(m, __shfl_down(m, off));
    if ((tid & 63) == 0) sred[tid >> 6] = m;
    __syncthreads();
    const float M = fmaxf(fmaxf(sred[0], sred[1]), fmaxf(sred[2], sred[3]));
    __syncthreads();

    float s = 0.f;
    for (int v = v0 + tid; v < v1; v += 256) s += __expf(row[v] - M);
#pragma unroll
    for (int off = 32; off > 0; off >>= 1) s += __shfl_down(s, off);
    if ((tid & 63) == 0) sred[tid >> 6] = s;
    __syncthreads();
    if (tid == 0) {
        pm[b * 8 + cx] = M;
        ps[b * 8 + cx] = sred[0] + sred[1] + sred[2] + sred[3];
    }
}

// final[b, v<V] = p_gen*softmax(logits); final[b, V..VEXT) = 0.
// Merges the 8 row-stat partials per block; computes p_gen from the fused
// accumulator; block (0,b) also writes o_pgen.
__global__ __launch_bounds__(256) void final_write(
    const float* __restrict__ logits, const float* __restrict__ pm,
    const float* __restrict__ ps, const float* __restrict__ pgen_acc,
    const float* __restrict__ bpg, float* __restrict__ final,
    float* __restrict__ o_pgen)
{
    const int b = blockIdx.y;
    float M = -3.0e38f;
#pragma unroll
    for (int i = 0; i < 8; ++i) M = fmaxf(M, pm[b * 8 + i]);
    float S = 0.f;
#pragma unroll
    for (int i = 0; i < 8; ++i) S += ps[b * 8 + i] * __expf(pm[b * 8 + i] - M);
    const float pg = sigmoid_f(pgen_acc[b] + bpg[0]);
    if (blockIdx.x == 0 && threadIdx.x == 0) o_pgen[b] = pg;

    const int v0 = (blockIdx.x * 256 + threadIdx.x) << 2;
    if (v0 >= VX_) return;
    const float sc = pg / S;
    const float* row = logits + (long)b * V_;
    float* out = final + (long)b * VX_ + v0;
#pragma unroll
    for (int j = 0; j < 4; ++j) {
        const int v = v0 + j;
        if (v < VX_) out[j] = (v < V_) ? __expf(row[v] - M) * sc : 0.f;
    }
}

// scatter-add copy distribution
__global__ __launch_bounds__(256) void scatter_kernel(
    const int* __restrict__ ids, const float* __restrict__ attn,
    const float* __restrict__ pgen, float* __restrict__ final)
{
    const int s = blockIdx.x * 256 + threadIdx.x;
    const int b = blockIdx.y;
    if (s < 400) {
        const float v = (1.0f - pgen[b]) * attn[b * 400 + s];
        atomicAdd(final + (long)b * VX_ + ids[b * 400 + s], v);
    }
}

extern "C" void kernel_launch(void* const* d_in, const int* in_sizes, int n_in,
                              void* d_out, int out_size, void* d_ws, size_t ws_size,
                              hipStream_t stream)
{
    const float* input_emb  = (const float*)d_in[0];
    const float* input_feed = (const float*)d_in[1];
    const float* hidden     = (const float*)d_in[2];
    const float* context    = (const float*)d_in[3];
    const float* states     = (const float*)d_in[4];
    const float* sfeat      = (const float*)d_in[5];
    const float* mask       = (const float*)d_in[6];
    const float* cov        = (const float*)d_in[7];
    const int*   src_ids    = (const int*)d_in[8];
    const float* W_ic  = (const float*)d_in[9];
    const float* b_ic  = (const float*)d_in[10];
    const float* W_ih  = (const float*)d_in[11];
    const float* W_hh  = (const float*)d_in[12];
    const float* b_ih  = (const float*)d_in[13];
    const float* b_hh  = (const float*)d_in[14];
    const float* W_dec = (const float*)d_in[15];
    const float* b_att = (const float*)d_in[16];
    const float* v_att = (const float*)d_in[17];
    const float* w_c   = (const float*)d_in[18];
    const float* W_out = (const float*)d_in[19];
    const float* b_out = (const float*)d_in[20];
    const float* W_pg  = (const float*)d_in[21];
    const float* b_pg  = (const float*)d_in[22];
    const float* W_v   = (const float*)d_in[23];
    const float* b_v   = (const float*)d_in[24];

    float* out = (float*)d_out;
    float* o_final = out + OFF_FINAL;
    float* o_pgen  = out + OFF_PGEN;
    float* o_attn  = out + OFF_ATTN;
    float* o_cov   = out + OFF_COV;
    float* o_h1    = out + OFF_H1;
    float* o_c1    = out + OFF_C1;
    float* o_dec   = out + OFF_DEC;

    float* ws = (float*)d_ws;
    float* w_x      = ws;            // 128*512
    float* w_decfea = ws + 327680;   // 128*512
    float* w_e      = ws + 393216;   // 128*400
    float* w_ctx    = ws + 444416;   // 128*512
    float* w_logits = ws + 509952;   // 128*50257
    float* w_pm     = ws + 6943104;  // 1024
    float* w_ps     = ws + 6944128;  // 1024
    float* w_pga    = ws + 6945152;  // 128 (pgen accumulator)

    const dim3 blk(256);
    // zero split-K accumulators (w_x, w_decfea, o_dec) + pgen accumulator
    zero_bufs<<<256, blk, 0, stream>>>(w_x, w_decfea, o_dec, w_pga);
    // x = [emb, feed] @ W_ic^T + b_ic   (split-K: 8 n-tiles x 8 chunks)
    gemm_mfma<4><<<dim3(8, 8), blk, 0, stream>>>(
        input_emb, W_ic, 1024, 0, input_feed, W_ic, 1024, 512,
        b_ic, w_x, 512, nullptr, nullptr);
    // gates + LSTM fused -> h1, c1
    gates_lstm<<<16, blk, 0, stream>>>(w_x, hidden, W_ih, W_hh, b_ih, b_hh,
                                       context, o_h1, o_c1);
    // dec_fea = h1 @ W_dec^T + b_att   (split-K: 8 x 4)
    gemm_mfma<4><<<dim3(8, 4), blk, 0, stream>>>(
        o_h1, W_dec, 512, 0, nullptr, nullptr, 0, 0,
        b_att, w_decfea, 512, nullptr, nullptr);
    // attention
    attn_scores<<<12800, blk, 0, stream>>>(sfeat, w_decfea, cov, w_c, v_att, w_e);
    attn_softmax<<<128, blk, 0, stream>>>(w_e, mask, cov, o_attn, o_cov, w_ctx);
    ctx_kernel<<<512, blk, 0, stream>>>(o_attn, states, w_ctx);
    // dec_out = [h1, ctx] @ W_out^T + b_out   (split-K 8 x 8, fused p_gen dot)
    gemm_mfma<4><<<dim3(8, 8), blk, 0, stream>>>(
        o_h1, W_out, 1024, 0, w_ctx, W_out, 1024, 512,
        b_out, o_dec, 512, W_pg, w_pga);
    // vocab logits
    gemm_mfma<4><<<dim3(786, 1), blk, 0, stream>>>(
        o_dec, W_v, 512, 0, nullptr, nullptr, 0, 0,
        b_v, w_logits, 50257, nullptr, nullptr);
    row_stats_part<<<dim3(8, 128), blk, 0, stream>>>(w_logits, w_pm, w_ps);
    final_write<<<dim3(50, 128), blk, 0, stream>>>(w_logits, w_pm, w_ps, w_pga,
                                                   b_pg, o_final, o_pgen);
    scatter_kernel<<<dim3(2, 128), blk, 0, stream>>>(src_ids, o_attn, o_pgen, o_final);
}